// Round 9
// baseline (45.655 us; speedup 1.0000x reference)
//
#include <hip/hip_runtime.h>

typedef _Float16 h16;
typedef __attribute__((ext_vector_type(2))) h16 h2v;
typedef __attribute__((ext_vector_type(8))) h16 h8v;

constexpr int H_ = 60, W_ = 108, HW_ = 6480;

// Workspace byte offsets. Features position-major [pos][128] fp16 (256 B/row).
// All features pre-scaled by 128^-0.25 so every dot carries 1/sqrt(128).
// NOTE: L2 and L3 of each map are CONTIGUOUS (L3 = L2 + 103680) — the
// persistent lookup stages both with one copy.
constexpr unsigned B_F0T  = 0;
constexpr unsigned B_F1T  = 1658880;
constexpr unsigned B_F0L1 = 3317760;   // 30*54
constexpr unsigned B_F0L2 = 3732480;   // 15*27
constexpr unsigned B_F0L3 = 3836160;   // 7*13  (= B_F0L2 + 103680)
constexpr unsigned B_F1L1 = 3859456;
constexpr unsigned B_F1L2 = 4274176;
constexpr unsigned B_F1L3 = 4377856;   // (= B_F1L2 + 103680)

// ---------------------------------------------------------------------------
// Transpose [128][6480] f32 -> [6480][128] f16 (pre-scaled), both maps.
__global__ __launch_bounds__(256) void k_transpose(const float* __restrict__ f0,
                                                   const float* __restrict__ f1,
                                                   h16* __restrict__ ws) {
    __shared__ float lds[64 * 129];
    const float* src = blockIdx.y ? f1 : f0;
    h16* dst = (h16*)((char*)ws + (blockIdx.y ? B_F1T : B_F0T));
    const int p0 = blockIdx.x * 64;
    const int t  = threadIdx.x;
    const int pr = t & 63, cr = t >> 6;
    #pragma unroll
    for (int cb = 0; cb < 128; cb += 4) {
        int c = cb + cr, p = p0 + pr;
        if (p < HW_) lds[pr * 129 + c] = src[(size_t)c * HW_ + p];
    }
    __syncthreads();
    const float S = 0.29730177875068026f;   // 128^-0.25
    const int cw = t & 63, pw = t >> 6;     // cw indexes half2 pairs
    #pragma unroll
    for (int pb = 0; pb < 64; pb += 4) {
        int p = p0 + pb + pw;
        if (p < HW_) {
            float a = lds[(pb + pw) * 129 + 2 * cw] * S;
            float b = lds[(pb + pw) * 129 + 2 * cw + 1] * S;
            h2v v; v.x = (h16)a; v.y = (h16)b;
            ((h2v*)dst)[(size_t)p * 64 + cw] = v;
        }
    }
}

// ---------------------------------------------------------------------------
// Full pyramid in ONE launch. L1 = 2x2 avg; L2 = direct 4x4 of L0; L3 =
// direct 8x8 of L0 (identical to iterated 2x2 under floor semantics).
__global__ __launch_bounds__(256) void k_pyramid(h16* __restrict__ wsh) {
    char* ws = (char*)wsh;
    const int map = blockIdx.y;
    const char* s = ws + (map ? B_F1T : B_F0T);
    const int bid = blockIdx.x;
    const int t = threadIdx.x;

    if (bid < 102) {                    // ---- L1: 2x2, 1620 pos x 16 chunks
        const int idx = bid * 256 + t;
        if (idx >= 1620 * 16) return;
        const int pos = idx >> 4, q = idx & 15;
        const int y = pos / 54, x = pos - y * 54;
        const unsigned r0 = (unsigned)(2 * y * 108 + 2 * x) * 256 + q * 16;
        const unsigned r1 = r0 + 108 * 256;
        h8v a = *(const h8v*)(s + r0);
        h8v b = *(const h8v*)(s + r0 + 256);
        h8v c = *(const h8v*)(s + r1);
        h8v d = *(const h8v*)(s + r1 + 256);
        h8v o;
        #pragma unroll
        for (int k = 0; k < 8; ++k)
            o[k] = (h16)((((float)a[k] + (float)b[k]) + ((float)c[k] + (float)d[k])) * 0.25f);
        *(h8v*)(ws + (map ? B_F1L1 : B_F0L1) + (unsigned)pos * 256 + q * 16) = o;
    } else if (bid < 128) {             // ---- L2: direct 4x4, 405 pos x 16
        const int idx = (bid - 102) * 256 + t;
        if (idx >= 405 * 16) return;
        const int pos = idx >> 4, q = idx & 15;
        const int y = pos / 27, x = pos - y * 27;
        float acc[8] = {};
        #pragma unroll
        for (int dy = 0; dy < 4; ++dy) {
            #pragma unroll
            for (int dx = 0; dx < 4; ++dx) {
                h8v u = *(const h8v*)(s + (unsigned)((4 * y + dy) * 108 + 4 * x + dx) * 256 + q * 16);
                #pragma unroll
                for (int k = 0; k < 8; ++k) acc[k] += (float)u[k];
            }
        }
        h8v o;
        #pragma unroll
        for (int k = 0; k < 8; ++k) o[k] = (h16)(acc[k] * 0.0625f);
        *(h8v*)(ws + (map ? B_F1L2 : B_F0L2) + (unsigned)pos * 256 + q * 16) = o;
    } else {                            // ---- L3: direct 8x8, 1 wave per (pos, half)
        const int idx = (bid - 128) * 256 + t;
        if (idx >= 91 * 128) return;
        const int pos = idx >> 7;
        const int sub = idx & 127;
        const int half = sub >> 6, lane = sub & 63;
        const int j = lane >> 3, qq = (lane & 7) + half * 8;  // row j, chunk qq
        const int y = pos / 13, x = pos - y * 13;
        float acc[8] = {};
        #pragma unroll
        for (int dx = 0; dx < 8; ++dx) {
            h8v u = *(const h8v*)(s + (unsigned)((8 * y + j) * 108 + 8 * x + dx) * 256 + qq * 16);
            #pragma unroll
            for (int k = 0; k < 8; ++k) acc[k] += (float)u[k];
        }
        #pragma unroll
        for (int k = 0; k < 8; ++k) {   // reduce over rows j (lane bits 3..5)
            acc[k] += __shfl_xor(acc[k], 8);
            acc[k] += __shfl_xor(acc[k], 16);
            acc[k] += __shfl_xor(acc[k], 32);
        }
        if (j == 0) {
            h8v o;
            #pragma unroll
            for (int k = 0; k < 8; ++k) o[k] = (h16)(acc[k] * 0.015625f);
            *(h8v*)(ws + (map ? B_F1L3 : B_F0L3) + (unsigned)pos * 256 + qq * 16) = o;
        }
    }
}

// ---------------------------------------------------------------------------
template <int CTRL>
__device__ __forceinline__ float dpp_add(float x) {
    int y = __builtin_amdgcn_update_dpp(0, __builtin_bit_cast(int, x),
                                        CTRL, 0xF, 0xF, true);
    return x + __builtin_bit_cast(float, y);
}

__device__ __forceinline__ float dot_u4(uint4 u, uint4 s, float acc) {
    acc = __builtin_amdgcn_fdot2(__builtin_bit_cast(h2v, u.x),
                                 __builtin_bit_cast(h2v, s.x), acc, false);
    acc = __builtin_amdgcn_fdot2(__builtin_bit_cast(h2v, u.y),
                                 __builtin_bit_cast(h2v, s.y), acc, false);
    acc = __builtin_amdgcn_fdot2(__builtin_bit_cast(h2v, u.z),
                                 __builtin_bit_cast(h2v, s.z), acc, false);
    acc = __builtin_amdgcn_fdot2(__builtin_bit_cast(h2v, u.w),
                                 __builtin_bit_cast(h2v, s.w), acc, false);
    return acc;
}

// ---------------------------------------------------------------------------
// Persistent lookup: 256 blocks (1/CU, forced by 124KB dynamic LDS) x 512 thr.
// Each block stages its direction's ENTIRE lvl2+lvl3 (126976 B, contiguous in
// ws) into LDS once, then its 8 waves loop over 4-pixel runs. Global gather
// drops from 48KB to 32KB per pixel; lvl2/3 reads ride the LDS pipe (parallel
// with VMEM). Run ranges are block-chunked so per-CU TA bytes balance to +-4%.
__global__ __launch_bounds__(512, 2) void k_lookup2(const h16* __restrict__ wsh,
                                                    const float* __restrict__ flow0,
                                                    const float* __restrict__ flow1,
                                                    const float* __restrict__ embt,
                                                    float* __restrict__ out) {
    extern __shared__ char lds2[];   // 126976 B: lvl2 (103680) + lvl3 (23296)
    const char* ws = (const char*)wsh;
    const int bid = blockIdx.x;
    const int xcd = bid & 7;
    const int dir = xcd >> 2;                        // XCDs 0-3: dir0, 4-7: dir1
    const int dirblk = (bid >> 3) * 4 + (xcd & 3);   // 0..127 within dir
    const int t = threadIdx.x;
    const int L = t & 63;
    const int wv = t >> 6;

    // stage lvl2+lvl3 of the gather map (contiguous 126976 B)
    {
        const uint4* src = (const uint4*)(ws + (dir ? B_F0L2 : B_F1L2));
        #pragma unroll
        for (int i = 0; i < 16; ++i) {
            const int c = t + i * 512;
            if (c < 7936) ((uint4*)lds2)[c] = src[c];
        }
    }

    const float e = embt[0];
    const float scale = dir ? 1.0f / (1.0f - e) : 1.0f / e;
    const float* fl = dir ? flow0 : flow1;
    const unsigned sB  = dir ? B_F1T : B_F0T;    // source features (own map)
    const unsigned gB0 = dir ? B_F0T : B_F1T;    // gather lvl0
    const unsigned gB1 = dir ? B_F0L1 : B_F1L1;  // gather lvl1

    const int ch = L & 7;        // 16B chunk index
    const int p  = L >> 3;       // window column 0..7

    __syncthreads();             // LDS ready

    // 4-pixel runs, block-chunked then wave round-robin
    const int rbeg = (dirblk * 1620) >> 7;
    const int rend = ((dirblk + 1) * 1620) >> 7;

    for (int r = rbeg + wv; r < rend; r += 8) {
        const int px0 = r * 4;

        // prefetch flow + source-feature chunks for all 4 pixels
        float cxa[4], cya[4];
        uint4 su0a[4], su1a[4];
        #pragma unroll
        for (int pp = 0; pp < 4; ++pp) {
            const int pix = px0 + pp;
            const int hh = pix / 108, ww = pix - hh * 108;
            cxa[pp] = (float)ww + fl[pix] * scale;
            cya[pp] = (float)hh + fl[HW_ + pix] * scale;
            const unsigned sbase = sB + (unsigned)pix * 256;
            su0a[pp] = *(const uint4*)(ws + sbase + ch * 16);
            su1a[pp] = *(const uint4*)(ws + sbase + 128 + ch * 16);
        }

        float vals[4][4];   // [lvl][pp]; lane L<49 holds channel lvl*49+L
        #pragma unroll
        for (int pp = 0; pp < 4; ++pp) {
            const float cx = cxa[pp], cy = cya[pp];
            const uint4 su0 = su0a[pp], su1 = su1a[pp];
            #pragma unroll
            for (int lvl = 0; lvl < 4; ++lvl) {
                const int wl = 108 >> lvl, hl = 60 >> lvl;
                const float inv = (lvl == 0) ? 1.f : (lvl == 1) ? 0.5f
                                : (lvl == 2) ? 0.25f : 0.125f;
                const float cxl = cx * inv, cyl = cy * inv;
                const float bxf = floorf(cxl), byf = floorf(cyl);
                const int bx = (int)bxf, by = (int)byf;
                const int gx = bx - 3 + p;
                const int gxc = min(max(gx, 0), wl - 1);
                const bool colv = (gx >= 0) & (gx < wl);
                const int gyo = by - 3 + ch;
                const bool ownv = colv & (gyo >= 0) & (gyo < hl);

                uint4 u0[8], u1[8];
                if (lvl >= 2) {          // LDS-resident levels
                    const char* base = (lvl == 3) ? (lds2 + 103680) : lds2;
                    const unsigned co = (unsigned)gxc * 256 + (unsigned)ch * 16;
                    #pragma unroll
                    for (int j = 0; j < 8; ++j) {
                        const int gy = by - 3 + j;
                        const int gyc = min(max(gy, 0), hl - 1);
                        const unsigned ro = co + (unsigned)(gyc * wl) * 256;
                        u0[j] = *(const uint4*)(base + ro);
                        u1[j] = *(const uint4*)(base + ro + 128);
                    }
                } else {                 // global gather levels
                    const unsigned gbase = (lvl == 0) ? gB0 : gB1;
                    const unsigned coloff = gbase + (unsigned)gxc * 256 + (unsigned)ch * 16;
                    #pragma unroll
                    for (int j = 0; j < 8; ++j) {
                        const int gy = by - 3 + j;
                        const int gyc = min(max(gy, 0), hl - 1);
                        const unsigned ro = coloff + (unsigned)(gyc * wl) * 256;
                        u0[j] = *(const uint4*)(ws + ro);
                        u1[j] = *(const uint4*)(ws + ro + 128);
                    }
                }

                float dval = 0.0f;
                #pragma unroll
                for (int j = 0; j < 8; ++j) {
                    float a0 = dot_u4(u0[j], su0, 0.0f);
                    float a1 = dot_u4(u1[j], su1, 0.0f);
                    float acc = a0 + a1;
                    acc = dpp_add<0xB1>(acc);    // quad_perm xor1
                    acc = dpp_add<0x4E>(acc);    // quad_perm xor2
                    acc = dpp_add<0x141>(acc);   // ROW_HALF_MIRROR (xor4 here)
                    dval = (ch == j) ? acc : dval;
                }
                dval = ownv ? dval : 0.0f;

                // bilinear: tap (row,col) lives in lane 8*col+row
                const int dyi = L / 7, dxi = L - dyi * 7;
                const float fx = cxl - bxf, fy = cyl - byf;
                const float d00 = __shfl(dval, 8 * dxi + dyi);
                const float d01 = __shfl(dval, 8 * dxi + dyi + 8);
                const float d10 = __shfl(dval, 8 * dxi + dyi + 1);
                const float d11 = __shfl(dval, 8 * dxi + dyi + 9);
                vals[lvl][pp] = (d00 * (1.0f - fx) + d01 * fx) * (1.0f - fy) +
                                (d10 * (1.0f - fx) + d11 * fx) * fy;
            }
        }

        // coalesced writes: lane L<49 owns channel lvl*49+L, 16B per level
        #pragma unroll
        for (int lvl = 0; lvl < 4; ++lvl)
            if (L < 49)
                *(float4*)(out + (size_t)(dir * 196 + lvl * 49 + L) * HW_ + px0) =
                    make_float4(vals[lvl][0], vals[lvl][1], vals[lvl][2], vals[lvl][3]);
        if (dir == 0 && L >= 49 && L < 53) {
            const int c = L - 49;
            const float* f = (c < 2) ? flow0 + (size_t)c * HW_
                                     : flow1 + (size_t)(c - 2) * HW_;
            *(float4*)(out + (size_t)(392 + c) * HW_ + px0) = *(const float4*)(f + px0);
        }
    }
}

// ---------------------------------------------------------------------------
extern "C" void kernel_launch(void* const* d_in, const int* in_sizes, int n_in,
                              void* d_out, int out_size, void* d_ws, size_t ws_size,
                              hipStream_t stream) {
    const float* fmap0 = (const float*)d_in[0];
    const float* fmap1 = (const float*)d_in[1];
    const float* flow0 = (const float*)d_in[2];
    const float* flow1 = (const float*)d_in[3];
    const float* embt  = (const float*)d_in[4];
    h16* ws  = (h16*)d_ws;
    float* out = (float*)d_out;

    // allow >64KB dynamic LDS for the persistent lookup (idempotent)
    (void)hipFuncSetAttribute((const void*)k_lookup2,
                              hipFuncAttributeMaxDynamicSharedMemorySize, 126976);

    k_transpose<<<dim3(102, 2), 256, 0, stream>>>(fmap0, fmap1, ws);
    k_pyramid<<<dim3(174, 2), 256, 0, stream>>>(ws);
    k_lookup2<<<dim3(256), 512, 126976, stream>>>(ws, flow0, flow1, embt, out);
}

// Round 11
// 42.277 us; speedup vs baseline: 1.0799x; 1.0799x over previous
//
#include <hip/hip_runtime.h>

typedef _Float16 h16;
typedef __attribute__((ext_vector_type(2))) h16 h2v;
typedef __attribute__((ext_vector_type(8))) h16 h8v;

constexpr int H_ = 60, W_ = 108, HW_ = 6480;

// Workspace byte offsets. Features position-major [pos][128] fp16 (256 B/row).
// All features pre-scaled by 128^-0.25 so every dot carries 1/sqrt(128).
// L2 and L3 of each map are CONTIGUOUS (L3 = L2 + 103680).
constexpr unsigned B_F0T  = 0;
constexpr unsigned B_F1T  = 1658880;
constexpr unsigned B_F0L1 = 3317760;   // 30*54
constexpr unsigned B_F0L2 = 3732480;   // 15*27
constexpr unsigned B_F0L3 = 3836160;   // 7*13  (= B_F0L2 + 103680)
constexpr unsigned B_F1L1 = 3859456;
constexpr unsigned B_F1L2 = 4274176;
constexpr unsigned B_F1L3 = 4377856;   // (= B_F1L2 + 103680)

constexpr unsigned LDS_L3  = 103680;   // lvl3 offset inside staged region
constexpr unsigned LDS_TOT = 126976;   // R9-proven allocation

// ---------------------------------------------------------------------------
// Transpose [128][6480] f32 -> [6480][128] f16 (pre-scaled), both maps.
__global__ __launch_bounds__(256) void k_transpose(const float* __restrict__ f0,
                                                   const float* __restrict__ f1,
                                                   h16* __restrict__ ws) {
    __shared__ float lds[64 * 129];
    const float* src = blockIdx.y ? f1 : f0;
    h16* dst = (h16*)((char*)ws + (blockIdx.y ? B_F1T : B_F0T));
    const int p0 = blockIdx.x * 64;
    const int t  = threadIdx.x;
    const int pr = t & 63, cr = t >> 6;
    #pragma unroll
    for (int cb = 0; cb < 128; cb += 4) {
        int c = cb + cr, p = p0 + pr;
        if (p < HW_) lds[pr * 129 + c] = src[(size_t)c * HW_ + p];
    }
    __syncthreads();
    const float S = 0.29730177875068026f;   // 128^-0.25
    const int cw = t & 63, pw = t >> 6;     // cw indexes half2 pairs
    #pragma unroll
    for (int pb = 0; pb < 64; pb += 4) {
        int p = p0 + pb + pw;
        if (p < HW_) {
            float a = lds[(pb + pw) * 129 + 2 * cw] * S;
            float b = lds[(pb + pw) * 129 + 2 * cw + 1] * S;
            h2v v; v.x = (h16)a; v.y = (h16)b;
            ((h2v*)dst)[(size_t)p * 64 + cw] = v;
        }
    }
}

// ---------------------------------------------------------------------------
// Full pyramid in ONE launch. L1 = 2x2 avg; L2 = direct 4x4 of L0; L3 =
// direct 8x8 of L0 (identical to iterated 2x2 under floor semantics).
__global__ __launch_bounds__(256) void k_pyramid(h16* __restrict__ wsh) {
    char* ws = (char*)wsh;
    const int map = blockIdx.y;
    const char* s = ws + (map ? B_F1T : B_F0T);
    const int bid = blockIdx.x;
    const int t = threadIdx.x;

    if (bid < 102) {                    // ---- L1: 2x2, 1620 pos x 16 chunks
        const int idx = bid * 256 + t;
        if (idx >= 1620 * 16) return;
        const int pos = idx >> 4, q = idx & 15;
        const int y = pos / 54, x = pos - y * 54;
        const unsigned r0 = (unsigned)(2 * y * 108 + 2 * x) * 256 + q * 16;
        const unsigned r1 = r0 + 108 * 256;
        h8v a = *(const h8v*)(s + r0);
        h8v b = *(const h8v*)(s + r0 + 256);
        h8v c = *(const h8v*)(s + r1);
        h8v d = *(const h8v*)(s + r1 + 256);
        h8v o;
        #pragma unroll
        for (int k = 0; k < 8; ++k)
            o[k] = (h16)((((float)a[k] + (float)b[k]) + ((float)c[k] + (float)d[k])) * 0.25f);
        *(h8v*)(ws + (map ? B_F1L1 : B_F0L1) + (unsigned)pos * 256 + q * 16) = o;
    } else if (bid < 128) {             // ---- L2: direct 4x4, 405 pos x 16
        const int idx = (bid - 102) * 256 + t;
        if (idx >= 405 * 16) return;
        const int pos = idx >> 4, q = idx & 15;
        const int y = pos / 27, x = pos - y * 27;
        float acc[8] = {};
        #pragma unroll
        for (int dy = 0; dy < 4; ++dy) {
            #pragma unroll
            for (int dx = 0; dx < 4; ++dx) {
                h8v u = *(const h8v*)(s + (unsigned)((4 * y + dy) * 108 + 4 * x + dx) * 256 + q * 16);
                #pragma unroll
                for (int k = 0; k < 8; ++k) acc[k] += (float)u[k];
            }
        }
        h8v o;
        #pragma unroll
        for (int k = 0; k < 8; ++k) o[k] = (h16)(acc[k] * 0.0625f);
        *(h8v*)(ws + (map ? B_F1L2 : B_F0L2) + (unsigned)pos * 256 + q * 16) = o;
    } else {                            // ---- L3: direct 8x8, 1 wave per (pos, half)
        const int idx = (bid - 128) * 256 + t;
        if (idx >= 91 * 128) return;
        const int pos = idx >> 7;
        const int sub = idx & 127;
        const int half = sub >> 6, lane = sub & 63;
        const int j = lane >> 3, qq = (lane & 7) + half * 8;  // row j, chunk qq
        const int y = pos / 13, x = pos - y * 13;
        float acc[8] = {};
        #pragma unroll
        for (int dx = 0; dx < 8; ++dx) {
            h8v u = *(const h8v*)(s + (unsigned)((8 * y + j) * 108 + 8 * x + dx) * 256 + qq * 16);
            #pragma unroll
            for (int k = 0; k < 8; ++k) acc[k] += (float)u[k];
        }
        #pragma unroll
        for (int k = 0; k < 8; ++k) {   // reduce over rows j (lane bits 3..5)
            acc[k] += __shfl_xor(acc[k], 8);
            acc[k] += __shfl_xor(acc[k], 16);
            acc[k] += __shfl_xor(acc[k], 32);
        }
        if (j == 0) {
            h8v o;
            #pragma unroll
            for (int k = 0; k < 8; ++k) o[k] = (h16)(acc[k] * 0.015625f);
            *(h8v*)(ws + (map ? B_F1L3 : B_F0L3) + (unsigned)pos * 256 + qq * 16) = o;
        }
    }
}

// ---------------------------------------------------------------------------
template <int CTRL>
__device__ __forceinline__ float dpp_add(float x) {
    int y = __builtin_amdgcn_update_dpp(0, __builtin_bit_cast(int, x),
                                        CTRL, 0xF, 0xF, true);
    return x + __builtin_bit_cast(float, y);
}

__device__ __forceinline__ float dot_u4(uint4 u, uint4 s, float acc) {
    acc = __builtin_amdgcn_fdot2(__builtin_bit_cast(h2v, u.x),
                                 __builtin_bit_cast(h2v, s.x), acc, false);
    acc = __builtin_amdgcn_fdot2(__builtin_bit_cast(h2v, u.y),
                                 __builtin_bit_cast(h2v, s.y), acc, false);
    acc = __builtin_amdgcn_fdot2(__builtin_bit_cast(h2v, u.z),
                                 __builtin_bit_cast(h2v, s.z), acc, false);
    acc = __builtin_amdgcn_fdot2(__builtin_bit_cast(h2v, u.w),
                                 __builtin_bit_cast(h2v, s.w), acc, false);
    return acc;
}

// ---------------------------------------------------------------------------
// Persistent lookup v3: 256 blocks x 1024 threads (16 waves, 1 block/CU).
// Block stages its gather map's lvl2+lvl3 (126976 B) once; owns ~50-51
// contiguous pixels, processed in 4 passes x 16 waves (1 pixel/wave/pass),
// results kept in registers. After ALL gathers finish, the dead LDS region
// is reused as so[196][53] for a fully coalesced write-out.
__global__ __launch_bounds__(1024, 1) void k_lookup3(const h16* __restrict__ wsh,
                                                     const float* __restrict__ flow0,
                                                     const float* __restrict__ flow1,
                                                     const float* __restrict__ embt,
                                                     float* __restrict__ out) {
    extern __shared__ char lds2[];
    const char* ws = (const char*)wsh;
    const int bid = blockIdx.x;
    const int xcd = bid & 7;
    const int dir = xcd >> 2;                        // XCDs 0-3: dir0, 4-7: dir1
    const int dirblk = (bid >> 3) * 4 + (xcd & 3);   // 0..127 within dir
    const int t = threadIdx.x;
    const int L = t & 63;
    const int wv = t >> 6;                           // 0..15

    // stage lvl2+lvl3 of the gather map (contiguous 126976 B = 7936 uint4)
    {
        const uint4* src = (const uint4*)(ws + (dir ? B_F0L2 : B_F1L2));
        #pragma unroll
        for (int i = 0; i < 8; ++i) {
            const int c = t + i * 1024;
            if (c < 7936) ((uint4*)lds2)[c] = src[c];
        }
    }

    const int rbeg = (dirblk * 6480) >> 7;           // pixel range of this block
    const int rend = ((dirblk + 1) * 6480) >> 7;
    const int npix = rend - rbeg;                    // 50 or 51

    const float e = embt[0];
    const float scale = dir ? 1.0f / (1.0f - e) : 1.0f / e;
    const float* fl = dir ? flow0 : flow1;
    const unsigned sB  = dir ? B_F1T : B_F0T;    // source features (own map)
    const unsigned gB0 = dir ? B_F0T : B_F1T;    // gather lvl0
    const unsigned gB1 = dir ? B_F0L1 : B_F1L1;  // gather lvl1

    const int ch = L & 7;        // 16B chunk index
    const int p  = L >> 3;       // window column 0..7

    __syncthreads();             // staged lvl2/3 ready

    float vals[4][4];            // [pass][lvl]

    #pragma unroll
    for (int ps = 0; ps < 4; ++ps) {
        const int lpix = ps * 16 + wv;       // block-local pixel index
        const int pix = rbeg + lpix;
        const bool act = (lpix < npix);

        float cx = 0.f, cy = 0.f;
        uint4 su0 = {}, su1 = {};
        if (act) {
            const int hh = pix / 108, ww = pix - hh * 108;
            cx = (float)ww + fl[pix] * scale;
            cy = (float)hh + fl[HW_ + pix] * scale;
            const unsigned sbase = sB + (unsigned)pix * 256;
            su0 = *(const uint4*)(ws + sbase + ch * 16);
            su1 = *(const uint4*)(ws + sbase + 128 + ch * 16);

            #pragma unroll
            for (int lvl = 0; lvl < 4; ++lvl) {
                const int wl = 108 >> lvl, hl = 60 >> lvl;
                const float inv = (lvl == 0) ? 1.f : (lvl == 1) ? 0.5f
                                : (lvl == 2) ? 0.25f : 0.125f;
                const float cxl = cx * inv, cyl = cy * inv;
                const float bxf = floorf(cxl), byf = floorf(cyl);
                const int bx = (int)bxf, by = (int)byf;
                const int gx = bx - 3 + p;
                const int gxc = min(max(gx, 0), wl - 1);
                const bool colv = (gx >= 0) & (gx < wl);

                uint4 u0[8], u1[8];
                if (lvl >= 2) {              // LDS-resident levels
                    const char* base = lds2 + ((lvl == 3) ? LDS_L3 : 0);
                    const unsigned co = (unsigned)gxc * 256 + (unsigned)ch * 16;
                    #pragma unroll
                    for (int j = 0; j < 8; ++j) {
                        const int gy = by - 3 + j;
                        const int gyc = min(max(gy, 0), hl - 1);
                        const unsigned ro = co + (unsigned)(gyc * wl) * 256;
                        u0[j] = *(const uint4*)(base + ro);
                        u1[j] = *(const uint4*)(base + ro + 128);
                    }
                } else {                     // global gather levels
                    const unsigned gbase = lvl ? gB1 : gB0;
                    const unsigned coloff = gbase + (unsigned)gxc * 256 + (unsigned)ch * 16;
                    #pragma unroll
                    for (int j = 0; j < 8; ++j) {
                        const int gy = by - 3 + j;
                        const int gyc = min(max(gy, 0), hl - 1);
                        const unsigned ro = coloff + (unsigned)(gyc * wl) * 256;
                        u0[j] = *(const uint4*)(ws + ro);
                        u1[j] = *(const uint4*)(ws + ro + 128);
                    }
                }

                float dval = 0.0f;
                #pragma unroll
                for (int j = 0; j < 8; ++j) {
                    float acc = dot_u4(u0[j], su0, 0.0f) + dot_u4(u1[j], su1, 0.0f);
                    acc = dpp_add<0xB1>(acc);    // quad_perm xor1
                    acc = dpp_add<0x4E>(acc);    // quad_perm xor2
                    acc = dpp_add<0x141>(acc);   // ROW_HALF_MIRROR (xor4 here)
                    dval = (ch == j) ? acc : dval;
                }
                const int gyo = by - 3 + ch;
                dval = (colv & (gyo >= 0) & (gyo < hl)) ? dval : 0.0f;

                // bilinear: tap (row,col) lives in lane 8*col+row
                const int dyi = L / 7, dxi = L - dyi * 7;
                const float fx = cxl - bxf, fy = cyl - byf;
                const float d00 = __shfl(dval, 8 * dxi + dyi);
                const float d01 = __shfl(dval, 8 * dxi + dyi + 8);
                const float d10 = __shfl(dval, 8 * dxi + dyi + 1);
                const float d11 = __shfl(dval, 8 * dxi + dyi + 9);
                vals[ps][lvl] = (d00 * (1.0f - fx) + d01 * fx) * (1.0f - fy) +
                                (d10 * (1.0f - fx) + d11 * fx) * fy;
            }
        }
    }

    __syncthreads();             // ALL gathers (incl. LDS lvl2/3 reads) done

    // reuse dead staged region as so[196][53] (41552 B < 126976 B)
    float* so = (float*)lds2;
    if (L < 49) {
        #pragma unroll
        for (int ps = 0; ps < 4; ++ps) {
            const int lpix = ps * 16 + wv;
            if (lpix < npix) {
                #pragma unroll
                for (int lvl = 0; lvl < 4; ++lvl)
                    so[(lvl * 49 + L) * 53 + lpix] = vals[ps][lvl];
            }
        }
    }

    __syncthreads();

    // coalesced write-out: 196 channels x npix floats
    for (int idx = t; idx < 196 * npix; idx += 1024) {
        const int chn = idx / npix;
        const int px  = idx - chn * npix;
        out[(size_t)(dir * 196 + chn) * HW_ + rbeg + px] = so[chn * 53 + px];
    }
    if (dir == 0) {
        for (int idx = t; idx < 4 * npix; idx += 1024) {
            const int c  = idx / npix;
            const int px = idx - c * npix;
            const float* f = (c < 2) ? flow0 + (size_t)c * HW_
                                     : flow1 + (size_t)(c - 2) * HW_;
            out[(size_t)(392 + c) * HW_ + rbeg + px] = f[rbeg + px];
        }
    }
}

// ---------------------------------------------------------------------------
extern "C" void kernel_launch(void* const* d_in, const int* in_sizes, int n_in,
                              void* d_out, int out_size, void* d_ws, size_t ws_size,
                              hipStream_t stream) {
    const float* fmap0 = (const float*)d_in[0];
    const float* fmap1 = (const float*)d_in[1];
    const float* flow0 = (const float*)d_in[2];
    const float* flow1 = (const float*)d_in[3];
    const float* embt  = (const float*)d_in[4];
    h16* ws  = (h16*)d_ws;
    float* out = (float*)d_out;

    (void)hipFuncSetAttribute((const void*)k_lookup3,
                              hipFuncAttributeMaxDynamicSharedMemorySize, LDS_TOT);

    k_transpose<<<dim3(102, 2), 256, 0, stream>>>(fmap0, fmap1, ws);
    k_pyramid<<<dim3(174, 2), 256, 0, stream>>>(ws);
    k_lookup3<<<dim3(256), 1024, LDS_TOT, stream>>>(ws, flow0, flow1, embt, out);
}